// Round 7
// baseline (93.293 us; speedup 1.0000x reference)
//
#include <hip/hip_runtime.h>

// GCN layer: out = relu( segment_sum( (h@W * norm)[src], dst ) * norm + b )
//
// Pipeline:
//   K0 wconv        : Wtg = bf16(W) in MFMA B-fragment order; zero gcur[]
//   K1 gemm_and_bin : grid-fused:
//                     blocks [0, nrb)      : scaledh = bf16((h@W)*norm) via MFMA
//                     blocks [nrb, +nbinb) : two-pass bin of edges by dst>>6
//                     (LDS count -> one global atomic per (block,bucket) -> rank+emit)
//   K2 bucket_reduce: per-bucket LDS counting sort, then group-owns-node gather:
//                     16 lanes/edge (uint2 = 4 bf16 ch/lane), 4 nodes per wave
//                     instruction, A/B node-set interleave -> 4 loads in flight,
//                     no shuffles, fused *norm+b, relu float4 store.

typedef unsigned int u32;
typedef unsigned short u16;
typedef __attribute__((ext_vector_type(8))) short s16x8;   // 8 bf16 = 4 VGPR
typedef __attribute__((ext_vector_type(4))) float f32x4;

#define NB_LOG 6
#define NPB 64             // nodes per bucket
#define CAP 2048           // edge capacity per bucket (mean ~1024, sd ~32)
#define MAXB 2048          // max buckets supported (N <= 131072)
#define EPB 8192           // edges per bin block (256 thr x 32)
#define RT 256             // bucket_reduce threads (4 waves)

__device__ __forceinline__ float bf2f(u16 v) {
  return __uint_as_float(((u32)v) << 16);
}
__device__ __forceinline__ u16 f2bf(float f) {
  u32 u = __float_as_uint(f);
  return (u16)((u + 0x7fffu + ((u >> 16) & 1u)) >> 16);  // RNE
}
__device__ __forceinline__ void acc_bf16x4(float4& a, uint2 v) {
  a.x += __uint_as_float(v.x << 16);
  a.y += __uint_as_float(v.x & 0xFFFF0000u);
  a.z += __uint_as_float(v.y << 16);
  a.w += __uint_as_float(v.y & 0xFFFF0000u);
}

// ---- K0: W -> bf16 in B-fragment order; zero gcur ----
__global__ __launch_bounds__(256) void wconv(
    const float* __restrict__ W, u16* __restrict__ Wtg, u32* __restrict__ gcur) {
  int o = blockIdx.x * 256 + threadIdx.x;  // 0..8191
  int j = o & 7, col = (o >> 3) & 15, kq = (o >> 7) & 3, ks = (o >> 9) & 3,
      ct = (o >> 11) & 3;
  int k = ks * 32 + kq * 8 + j;
  int n = ct * 16 + col;
  Wtg[o] = f2bf(W[k * 64 + n]);
  if (o < MAXB) gcur[o] = 0;
}

// ---- K1: fused MFMA GEMM + edge binning ----
__global__ __launch_bounds__(256) void gemm_and_bin(
    const float* __restrict__ h, const float* __restrict__ norm,
    const u16* __restrict__ Wtg, u16* __restrict__ scaledh, int N, int nrb,
    const int* __restrict__ src, const int* __restrict__ dst,
    u32* __restrict__ gcur, u32* __restrict__ bins, int E) {
  __shared__ u32 hist[MAXB];   // 8 KB
  __shared__ u32 lbase[MAXB];  // 8 KB

  if ((int)blockIdx.x < nrb) {
    // ---- GEMM path: 64 rows/block (4 waves x 16 rows), 64 cols ----
    int lane = threadIdx.x & 63, wid = threadIdx.x >> 6;
    int col = lane & 15, kq = lane >> 4;

    s16x8 bfrag[4][4];
#pragma unroll
    for (int ct = 0; ct < 4; ++ct)
#pragma unroll
      for (int ks = 0; ks < 4; ++ks) {
        int f = ct * 16 + ks * 4 + kq;
        bfrag[ct][ks] =
            *reinterpret_cast<const s16x8*>(Wtg + ((size_t)(f * 16 + col) * 8));
      }

    int row0 = blockIdx.x * 64 + wid * 16;
    int myrow = row0 + col;
    int ldrow = myrow < N ? myrow : (N - 1);
    const float* __restrict__ hrow = h + (size_t)ldrow * 128 + kq * 8;

    f32x4 acc[4];
#pragma unroll
    for (int ct = 0; ct < 4; ++ct) acc[ct] = (f32x4){0.f, 0.f, 0.f, 0.f};

#pragma unroll
    for (int ks = 0; ks < 4; ++ks) {
      float4 x0 = *reinterpret_cast<const float4*>(hrow + ks * 32);
      float4 x1 = *reinterpret_cast<const float4*>(hrow + ks * 32 + 4);
      s16x8 a;
      a[0] = (short)f2bf(x0.x); a[1] = (short)f2bf(x0.y);
      a[2] = (short)f2bf(x0.z); a[3] = (short)f2bf(x0.w);
      a[4] = (short)f2bf(x1.x); a[5] = (short)f2bf(x1.y);
      a[6] = (short)f2bf(x1.z); a[7] = (short)f2bf(x1.w);
#pragma unroll
      for (int ct = 0; ct < 4; ++ct)
        acc[ct] =
            __builtin_amdgcn_mfma_f32_16x16x32_bf16(a, bfrag[ct][ks], acc[ct], 0, 0, 0);
    }

#pragma unroll
    for (int reg = 0; reg < 4; ++reg) {
      int node = row0 + kq * 4 + reg;
      if (node < N) {
        float nm = norm[node];
#pragma unroll
        for (int ct = 0; ct < 4; ++ct)
          scaledh[(size_t)node * 64 + ct * 16 + col] = f2bf(acc[ct][reg] * nm);
      }
    }
    return;
  }

  // ---- bin path: two-pass (count -> reserve -> rank+emit) ----
  int bid = (int)blockIdx.x - nrb;
  int t = threadIdx.x;
  for (int i = t; i < MAXB; i += 256) hist[i] = 0;
  __syncthreads();
  int e0 = bid * EPB;
#pragma unroll 4
  for (int k = 0; k < EPB / 256; ++k) {
    int e = e0 + k * 256 + t;  // coalesced
    if (e < E) atomicAdd(&hist[dst[e] >> NB_LOG], 1u);  // native ds_add
  }
  __syncthreads();
  for (int i = t; i < MAXB; i += 256) {
    u32 c = hist[i];
    lbase[i] = c ? atomicAdd(&gcur[i], c) : 0u;  // 1 global atomic per (block,bucket)
  }
  __syncthreads();
  for (int i = t; i < MAXB; i += 256) hist[i] = 0;
  __syncthreads();
#pragma unroll 4
  for (int k = 0; k < EPB / 256; ++k) {
    int e = e0 + k * 256 + t;
    if (e < E) {
      int d = dst[e], s = src[e];
      int bk = d >> NB_LOG;
      u32 p = lbase[bk] + atomicAdd(&hist[bk], 1u);  // per-(block,bucket) rank
      if (p < CAP)
        bins[(size_t)bk * CAP + p] = ((u32)s << NB_LOG) | (u32)(d & (NPB - 1));
    }
  }
}

// ---- K2: per-bucket counting sort + group-owns-node gather-reduce ----
__global__ __launch_bounds__(RT) void bucket_reduce(
    const u16* __restrict__ scaledh, const u32* __restrict__ bins,
    const u32* __restrict__ gcur, const float* __restrict__ norm,
    const float4* __restrict__ bias4, float* __restrict__ out, int N) {
  __shared__ u32 hist[NPB];
  __shared__ u32 startp[NPB + 1];
  __shared__ u32 sorted[CAP];
  int bkt = blockIdx.x;
  int t = threadIdx.x, lane = t & 63, wid = t >> 6;
  int cnt = (int)gcur[bkt];
  if (cnt > CAP) cnt = CAP;
  if (t < NPB) hist[t] = 0;
  __syncthreads();

  const u32* __restrict__ my = bins + (size_t)bkt * CAP;
  u32 w[CAP / RT];
  u32 rk[CAP / RT];
#pragma unroll
  for (int k = 0; k < CAP / RT; ++k) {
    int e = k * RT + t;  // coalesced
    w[k] = (e < cnt) ? my[e] : 0xFFFFFFFFu;
  }
#pragma unroll
  for (int k = 0; k < CAP / RT; ++k) {
    if (w[k] != 0xFFFFFFFFu)
      rk[k] = atomicAdd(&hist[w[k] & (NPB - 1)], 1u);  // native int LDS atomic
  }
  __syncthreads();
  // wave-level exclusive scan of hist[0..63] (wave 0)
  if (t < NPB) {
    u32 v = hist[t];
    u32 inc = v;
#pragma unroll
    for (int m = 1; m < NPB; m <<= 1) {
      u32 x = __shfl_up(inc, m);
      if (t >= m) inc += x;
    }
    startp[t] = inc - v;
    if (t == NPB - 1) startp[NPB] = inc;
  }
  __syncthreads();
#pragma unroll
  for (int k = 0; k < CAP / RT; ++k) {
    if (w[k] != 0xFFFFFFFFu)
      sorted[startp[w[k] & (NPB - 1)] + rk[k]] = w[k] >> NB_LOG;
  }
  __syncthreads();

  // Gather: 16-lane group owns one node; groups walk their own edge list
  // 2 edges per iter; A/B node-set interleave -> 4 independent loads in flight.
  int grp = lane >> 4, c4 = lane & 15;
  float4 bl = bias4[c4];
  int base = bkt << NB_LOG;
  int cm1 = cnt - 1;  // clamp for speculative LDS reads (loop empty if cnt==0)
#pragma unroll
  for (int round = 0; round < 2; ++round) {
    int rA = (wid << 4) + (round << 3) + grp;  // wave strip: 16 nodes
    int rB = rA + 4;
    int jA = (int)startp[rA], eA = (int)startp[rA + 1];
    int jB = (int)startp[rB], eB = (int)startp[rB + 1];
    float4 aA = make_float4(0.f, 0.f, 0.f, 0.f);
    float4 aB = make_float4(0.f, 0.f, 0.f, 0.f);
    while (jA < eA || jB < eB) {
      int iA0 = (int)sorted[min(jA, cm1)];
      int iA1 = (int)sorted[min(jA + 1, cm1)];
      int iB0 = (int)sorted[min(jB, cm1)];
      int iB1 = (int)sorted[min(jB + 1, cm1)];
      uint2 vA0 = *reinterpret_cast<const uint2*>(scaledh + ((size_t)iA0 << 6) + (c4 << 2));
      uint2 vA1 = *reinterpret_cast<const uint2*>(scaledh + ((size_t)iA1 << 6) + (c4 << 2));
      uint2 vB0 = *reinterpret_cast<const uint2*>(scaledh + ((size_t)iB0 << 6) + (c4 << 2));
      uint2 vB1 = *reinterpret_cast<const uint2*>(scaledh + ((size_t)iB1 << 6) + (c4 << 2));
      uint2 z = make_uint2(0u, 0u);
      vA0 = (jA < eA) ? vA0 : z;
      vA1 = (jA + 1 < eA) ? vA1 : z;
      vB0 = (jB < eB) ? vB0 : z;
      vB1 = (jB + 1 < eB) ? vB1 : z;
      acc_bf16x4(aA, vA0);
      acc_bf16x4(aA, vA1);
      acc_bf16x4(aB, vB0);
      acc_bf16x4(aB, vB1);
      jA += 2;
      jB += 2;
    }
    int nodeA = base + rA, nodeB = base + rB;
    if (nodeA < N) {
      float nm = norm[nodeA];
      float4 o;
      o.x = fmaxf(fmaf(aA.x, nm, bl.x), 0.f);
      o.y = fmaxf(fmaf(aA.y, nm, bl.y), 0.f);
      o.z = fmaxf(fmaf(aA.z, nm, bl.z), 0.f);
      o.w = fmaxf(fmaf(aA.w, nm, bl.w), 0.f);
      *reinterpret_cast<float4*>(out + (size_t)nodeA * 64 + (c4 << 2)) = o;
    }
    if (nodeB < N) {
      float nm = norm[nodeB];
      float4 o;
      o.x = fmaxf(fmaf(aB.x, nm, bl.x), 0.f);
      o.y = fmaxf(fmaf(aB.y, nm, bl.y), 0.f);
      o.z = fmaxf(fmaf(aB.z, nm, bl.z), 0.f);
      o.w = fmaxf(fmaf(aB.w, nm, bl.w), 0.f);
      *reinterpret_cast<float4*>(out + (size_t)nodeB * 64 + (c4 << 2)) = o;
    }
  }
}

// ---- fallback (atomic scatter) ----
__global__ __launch_bounds__(256) void zero_out(float4* __restrict__ o4, size_t n4) {
  size_t tid = blockIdx.x * 256 + threadIdx.x;
  size_t stride = (size_t)gridDim.x * 256;
  for (size_t i = tid; i < n4; i += stride) o4[i] = make_float4(0.f, 0.f, 0.f, 0.f);
}

__global__ __launch_bounds__(256) void scatter_edges(
    const u16* __restrict__ scaledh, const int* __restrict__ src,
    const int* __restrict__ dst, float* __restrict__ agg, int E) {
  int lane = threadIdx.x & 63;
  int gwid = (blockIdx.x * 256 + threadIdx.x) >> 6;
  int nw = (gridDim.x * 256) >> 6;
  for (int e = gwid; e < E; e += nw) {
    int s = __builtin_amdgcn_readfirstlane(src[e]);
    int d = __builtin_amdgcn_readfirstlane(dst[e]);
    float v = bf2f(scaledh[(size_t)s * 64 + lane]);
    unsafeAtomicAdd(&agg[(size_t)d * 64 + lane], v);
  }
}

__global__ __launch_bounds__(256) void finalize(
    float4* __restrict__ out4, const float* __restrict__ norm,
    const float4* __restrict__ b4, int N) {
  size_t total4 = (size_t)N * 16;
  size_t tid = blockIdx.x * 256 + threadIdx.x;
  size_t stride = (size_t)gridDim.x * 256;
  for (size_t t = tid; t < total4; t += stride) {
    int i = (int)(t >> 4), q = (int)(t & 15);
    float4 v = out4[t];
    float nm = norm[i];
    float4 bb = b4[q];
    v.x = fmaxf(fmaf(v.x, nm, bb.x), 0.f);
    v.y = fmaxf(fmaf(v.y, nm, bb.y), 0.f);
    v.z = fmaxf(fmaf(v.z, nm, bb.z), 0.f);
    v.w = fmaxf(fmaf(v.w, nm, bb.w), 0.f);
    out4[t] = v;
  }
}

extern "C" void kernel_launch(void* const* d_in, const int* in_sizes, int n_in,
                              void* d_out, int out_size, void* d_ws, size_t ws_size,
                              hipStream_t stream) {
  const float* h    = (const float*)d_in[0];
  const float* norm = (const float*)d_in[1];
  const float* W    = (const float*)d_in[2];
  const float* b    = (const float*)d_in[3];
  const int*   src  = (const int*)d_in[4];
  const int*   dst  = (const int*)d_in[5];

  int N = in_sizes[1];
  int E = in_sizes[4];
  int nbuckets = (N + NPB - 1) >> NB_LOG;
  int nrb = (N + 63) >> 6;
  int nbinb = (E + EPB - 1) / EPB;

  char* ws = (char*)d_ws;
  size_t off = 0;
  u16* scaledh = (u16*)(ws + off); off += (((size_t)N * 64 * 2) + 255) & ~(size_t)255;
  u32* gcur    = (u32*)(ws + off); off += (MAXB * 4 + 255) & ~(size_t)255;
  u16* Wtg     = (u16*)(ws + off); off += (8192 * 2 + 255) & ~(size_t)255;
  u32* bins    = (u32*)(ws + off); off += (size_t)MAXB * CAP * 4;
  size_t needed = off;
  size_t needed_fb = (size_t)((char*)bins - ws);  // fallback: scaledh+gcur+Wtg only

  if (ws_size >= needed && nbuckets <= MAXB) {
    wconv<<<32, 256, 0, stream>>>(W, Wtg, gcur);
    gemm_and_bin<<<nrb + nbinb, 256, 0, stream>>>(h, norm, Wtg, scaledh, N, nrb,
                                                  src, dst, gcur, bins, E);
    bucket_reduce<<<nbuckets, RT, 0, stream>>>(scaledh, bins, gcur, norm,
                                               (const float4*)b, (float*)d_out, N);
  } else if (ws_size >= needed_fb) {
    float* agg = (float*)d_out;
    wconv<<<32, 256, 0, stream>>>(W, Wtg, gcur);
    gemm_and_bin<<<nrb, 256, 0, stream>>>(h, norm, Wtg, scaledh, N, nrb,
                                          src, dst, gcur, bins, E);
    zero_out<<<1024, 256, 0, stream>>>((float4*)agg, (size_t)N * 16);
    scatter_edges<<<2048, 256, 0, stream>>>(scaledh, src, dst, agg, E);
    finalize<<<1024, 256, 0, stream>>>((float4*)agg, norm, (const float4*)b, N);
  }
}